// Round 9
// baseline (345.174 us; speedup 1.0000x reference)
//
#include <hip/hip_runtime.h>

// Problem constants: N=64, A=5, C=20, FM=52, M=32
#define N_IMG 64
#define NA 5
#define NC 20
#define FM 52
#define NM 32
#define FMFM (FM * FM)                  // 2704 (even)
#define Q2 (FMFM / 2)                   // 1352 float2 per channel plane
#define CELLS (NA * FMFM)               // 13520
#define TPI2 (CELLS / 2)                // 6760 threads/image, 2 cells each
#define BLOCK 256
#define BX2 ((TPI2 + BLOCK - 1) / BLOCK) // 27

__device__ __forceinline__ float frcp(float x) { return __builtin_amdgcn_rcpf(x); }
__device__ __forceinline__ float sl1(float a, float b) {
    float d = a - b;
    float ad = fabsf(d);
    return ad < 1.0f ? 0.5f * d * d : ad - 0.5f;
}
// Keep a loaded value live without consuming it (rule #17: prevents DCE of
// the load without adding work).
__device__ __forceinline__ void sink2(float2 v) {
    asm volatile("" :: "v"(v.x), "v"(v.y));
}

#define CLSJ(C) {                                                             \
    cmax.C = fmaxf(cmax.C, tv.C);                                             \
    float pr = __expf(lv.C) * inv.C;                                          \
    lacc.C += tv.C > 0.0f ? sl1(pr, tv.C) : 0.0f; }

#define HEADJ(C, JX) {                                                        \
    float sx = frcp(1.0f + __expf(-P0.C));                                    \
    float sy = frcp(1.0f + __expf(-P1.C));                                    \
    float ew = __expf(P2.C);                                                  \
    float eh = __expf(P3.C);                                                  \
    lacc.C += pos.C * (sl1(sx, T0.C) + sl1(sy, T1.C) +                        \
                       sl1(ew, T2.C) + sl1(eh, T3.C));                        \
    float bx = sx + (float)(xx + JX);                                         \
    float by = sy + (float)yy;                                                \
    float bw = aw * ew, bh = ah * eh;                                         \
    px1.C = bx - 0.5f * bw; py1.C = by - 0.5f * bh;                           \
    px2.C = bx + 0.5f * bw; py2.C = by + 0.5f * bh;                           \
    ap.C  = (px2.C - px1.C) * (py2.C - py1.C); }

#define IOUJ(C) {                                                             \
    float lx = fmaxf(px1.C, B.x), ly = fmaxf(py1.C, B.y);                     \
    float rx = fminf(px2.C, B.z), ry = fminf(py2.C, B.w);                     \
    float w_ = fmaxf(rx - lx, 0.0f), h_ = fmaxf(ry - ly, 0.0f);               \
    float it = w_ * h_;                                                       \
    float dn = ap.C + sa - it;                                                \
    bool gt = it * db.C > ib.C * dn;                                          \
    ib.C = gt ? it : ib.C;                                                    \
    db.C = gt ? dn : db.C; }

#define IOULOSSJ(C) {                                                         \
    float best  = ib.C * frcp(db.C);                                          \
    float ipred = frcp(1.0f + __expf(-P4.C));                                 \
    lacc.C += sl1(ipred * wgt.C, best * wgt.C); }

// MODE bit0 = class/softmax math; bit1 = head/IoU math.
// MODE==3 is the real kernel (identical to round-7's validated kernel) and
// the only one that writes acc. MODE 0/1/2 are rocprof ablation probes:
// identical loads, math subset, results asm-sunk, no side effects.
template<int MODE>
__global__ __launch_bounds__(BLOCK) void yolo_probe(
    const float* __restrict__ preds,
    const float* __restrict__ loc_t,
    const float* __restrict__ cls_t,
    const float4* __restrict__ box_t,
    const float* __restrict__ anchors,
    double* __restrict__ acc)
{
    constexpr bool DO_CLS = (MODE & 1) != 0;
    constexpr bool DO_BOX = (MODE & 2) != 0;

    __shared__ float4 sbox[NM];
    __shared__ float  sarea[NM];
    __shared__ double wsum[BLOCK / 64];
    __shared__ double wpos[BLOCK / 64];

    const int n = blockIdx.y;
    const int tid = threadIdx.x;

    if (tid < NM) {
        float4 b = box_t[n * NM + tid];
        sbox[tid] = b;
        sarea[tid] = (b.z - b.x) * (b.w - b.y);
    }
    __syncthreads();

    const int t = blockIdx.x * BLOCK + tid;
    float loss = 0.0f, posn = 0.0f;

    if (t < TPI2) {
        const int g   = t * 2;
        const int a   = g / FMFM;
        const int rem = g - a * FMFM;
        const int yy  = rem / FM;
        const int xx  = rem - yy * FM;
        const int q   = rem >> 1;

        const float2* pb = (const float2*)(preds + (size_t)(n * NA + a) * 25 * FMFM) + q;
        const float2* cb = (const float2*)(cls_t + (size_t)(n * NA + a) * NC * FMFM) + q;
        const float2* lb = (const float2*)(loc_t + (size_t)(n * NA + a) * 4  * FMFM) + q;

        float2 lacc = make_float2(0.f, 0.f);

        // ---- Pass 1: logit planes (softmax denominator when DO_CLS).
        float2 s = make_float2(0.f, 0.f);
        #pragma unroll 5
        for (int c = 0; c < NC; ++c) {
            float2 v = pb[(5 + c) * Q2];
            if (DO_CLS) { s.x += __expf(v.x); s.y += __expf(v.y); }
            else        sink2(v);
        }
        float2 inv = make_float2(frcp(s.x), frcp(s.y));

        const float2* pbo = pb;
        asm volatile("" : "+v"(pbo));

        // ---- Pass 2: logit re-read + cls targets (cls loss when DO_CLS).
        float2 cmax = make_float2(0.f, 0.f);
        #pragma unroll 4
        for (int c = 0; c < NC; ++c) {
            float2 lv = pbo[(5 + c) * Q2];
            float2 tv = cb[c * Q2];
            if (DO_CLS) { CLSJ(x) CLSJ(y) }
            else        { sink2(lv); sink2(tv); }
        }

        float2 pos, wgt;
        if (DO_CLS) {
            pos.x = cmax.x > 0.f ? 1.f : 0.f;  wgt.x = cmax.x > 0.f ? 1.f : 0.1f;
            pos.y = cmax.y > 0.f ? 1.f : 0.f;  wgt.y = cmax.y > 0.f ? 1.f : 0.1f;
        } else {
            pos = make_float2(1.f, 1.f); wgt = make_float2(1.f, 1.f);
        }
        posn = pos.x + pos.y;

        // ---- Phase 3/4: head channels + loc targets (+ IoU when DO_BOX).
        float2 P0 = pb[0 * Q2], P1 = pb[1 * Q2], P2 = pb[2 * Q2];
        float2 P3 = pb[3 * Q2], P4 = pb[4 * Q2];
        float2 T0 = lb[0 * Q2], T1 = lb[1 * Q2], T2 = lb[2 * Q2], T3 = lb[3 * Q2];

        if (DO_BOX) {
            const float aw = anchors[a * 2 + 0];
            const float ah = anchors[a * 2 + 1];
            float2 px1, py1, px2, py2, ap, ib, db;
            HEADJ(x, 0) HEADJ(y, 1)
            ib = make_float2(0.f, 0.f);
            db = make_float2(1.f, 1.f);
            #pragma unroll 4
            for (int tb = 0; tb < NM; ++tb) {
                float4 B = sbox[tb];
                float sa = sarea[tb];
                IOUJ(x) IOUJ(y)
            }
            IOULOSSJ(x) IOULOSSJ(y)
        } else {
            sink2(P0); sink2(P1); sink2(P2); sink2(P3); sink2(P4);
            sink2(T0); sink2(T1); sink2(T2); sink2(T3);
        }

        loss = lacc.x + lacc.y;
    }

    if (MODE == 3) {
        // Real kernel: reduce + atomic.
        double dl = (double)loss;
        double dp = (double)posn;
        #pragma unroll
        for (int off = 32; off > 0; off >>= 1) {
            dl += __shfl_down(dl, off);
            dp += __shfl_down(dp, off);
        }
        const int wave = tid >> 6, lane = tid & 63;
        if (lane == 0) { wsum[wave] = dl; wpos[wave] = dp; }
        __syncthreads();
        if (tid == 0) {
            double tl = 0.0, tp = 0.0;
            #pragma unroll
            for (int w = 0; w < BLOCK / 64; ++w) { tl += wsum[w]; tp += wpos[w]; }
            atomicAdd(&acc[0], tl);
            atomicAdd(&acc[1], tp);
        }
    } else {
        // Probe: keep results live, write nothing.
        asm volatile("" :: "v"(loss), "v"(posn));
    }
}

__global__ void yolo_loss_finalize(const double* __restrict__ acc,
                                   float* __restrict__ out) {
    out[0] = (float)(acc[0] / acc[1]);
}

extern "C" void kernel_launch(void* const* d_in, const int* in_sizes, int n_in,
                              void* d_out, int out_size, void* d_ws, size_t ws_size,
                              hipStream_t stream) {
    const float*  preds   = (const float*)d_in[0];
    const float*  loc_t   = (const float*)d_in[1];
    const float*  cls_t   = (const float*)d_in[2];
    const float4* box_t   = (const float4*)d_in[3];
    const float*  anchors = (const float*)d_in[4];
    double* acc = (double*)d_ws;

    hipMemsetAsync(d_ws, 0, 2 * sizeof(double), stream);

    dim3 grid(BX2, N_IMG);
    // Ablation probes (rocprof gives per-dispatch durations; results sunk):
    yolo_probe<0><<<grid, BLOCK, 0, stream>>>(preds, loc_t, cls_t, box_t, anchors, acc); // loads only
    yolo_probe<1><<<grid, BLOCK, 0, stream>>>(preds, loc_t, cls_t, box_t, anchors, acc); // + cls/softmax
    yolo_probe<2><<<grid, BLOCK, 0, stream>>>(preds, loc_t, cls_t, box_t, anchors, acc); // + head/IoU
    // Real kernel (validated round-7 structure):
    yolo_probe<3><<<grid, BLOCK, 0, stream>>>(preds, loc_t, cls_t, box_t, anchors, acc);
    yolo_loss_finalize<<<1, 1, 0, stream>>>(acc, (float*)d_out);
}

// Round 10
// 272.848 us; speedup vs baseline: 1.2651x; 1.2651x over previous
//
#include <hip/hip_runtime.h>

// Problem constants: N=64, A=5, C=20, FM=52, M=32
#define N_IMG 64
#define NA 5
#define NC 20
#define FM 52
#define NM 32
#define FMFM (FM * FM)                  // 2704 (even)
#define Q2 (FMFM / 2)                   // 1352 float2 per channel plane
#define CELLS (NA * FMFM)               // 13520
#define TPI2 (CELLS / 2)                // 6760 threads/image, 2 cells each
#define BLOCK 256
#define BX2 ((TPI2 + BLOCK - 1) / BLOCK) // 27

__device__ __forceinline__ float frcp(float x) { return __builtin_amdgcn_rcpf(x); }
__device__ __forceinline__ float sl1(float a, float b) {
    float d = a - b;
    float ad = fabsf(d);
    return ad < 1.0f ? 0.5f * d * d : ad - 0.5f;
}
__device__ __forceinline__ void sink2(float2 v) {
    asm volatile("" :: "v"(v.x), "v"(v.y));
}
__device__ __forceinline__ void sink4(float4 v) {
    asm volatile("" :: "v"(v.x), "v"(v.y), "v"(v.z), "v"(v.w));
}

#define CLSJ(C) {                                                             \
    cmax.C = fmaxf(cmax.C, tv.C);                                             \
    float pr = __expf(lv.C) * inv.C;                                          \
    lacc.C += tv.C > 0.0f ? sl1(pr, tv.C) : 0.0f; }

#define HEADJ(C, JX) {                                                        \
    float sx = frcp(1.0f + __expf(-P0.C));                                    \
    float sy = frcp(1.0f + __expf(-P1.C));                                    \
    float ew = __expf(P2.C);                                                  \
    float eh = __expf(P3.C);                                                  \
    lacc.C += pos.C * (sl1(sx, T0.C) + sl1(sy, T1.C) +                        \
                       sl1(ew, T2.C) + sl1(eh, T3.C));                        \
    float bx = sx + (float)(xx + JX);                                         \
    float by = sy + (float)yy;                                                \
    float bw = aw * ew, bh = ah * eh;                                         \
    px1.C = bx - 0.5f * bw; py1.C = by - 0.5f * bh;                           \
    px2.C = bx + 0.5f * bw; py2.C = by + 0.5f * bh;                           \
    ap.C  = (px2.C - px1.C) * (py2.C - py1.C); }

#define IOUJ(C) {                                                             \
    float lx = fmaxf(px1.C, B.x), ly = fmaxf(py1.C, B.y);                     \
    float rx = fminf(px2.C, B.z), ry = fminf(py2.C, B.w);                     \
    float w_ = fmaxf(rx - lx, 0.0f), h_ = fmaxf(ry - ly, 0.0f);               \
    float it = w_ * h_;                                                       \
    float dn = ap.C + sa - it;                                                \
    bool gt = it * db.C > ib.C * dn;                                          \
    ib.C = gt ? it : ib.C;                                                    \
    db.C = gt ? dn : db.C; }

#define IOULOSSJ(C) {                                                         \
    float best  = ib.C * frcp(db.C);                                          \
    float ipred = frcp(1.0f + __expf(-P4.C));                                 \
    lacc.C += sl1(ipred * wgt.C, best * wgt.C); }

// ======================= REAL KERNEL (r7, validated) =======================
__global__ __launch_bounds__(BLOCK) void yolo_full(
    const float* __restrict__ preds,
    const float* __restrict__ loc_t,
    const float* __restrict__ cls_t,
    const float4* __restrict__ box_t,
    const float* __restrict__ anchors,
    double* __restrict__ acc)
{
    __shared__ float4 sbox[NM];
    __shared__ float  sarea[NM];
    __shared__ double wsum[BLOCK / 64];
    __shared__ double wpos[BLOCK / 64];

    const int n = blockIdx.y;
    const int tid = threadIdx.x;

    if (tid < NM) {
        float4 b = box_t[n * NM + tid];
        sbox[tid] = b;
        sarea[tid] = (b.z - b.x) * (b.w - b.y);
    }
    __syncthreads();

    const int t = blockIdx.x * BLOCK + tid;
    float loss = 0.0f, posn = 0.0f;

    if (t < TPI2) {
        const int g   = t * 2;
        const int a   = g / FMFM;
        const int rem = g - a * FMFM;
        const int yy  = rem / FM;
        const int xx  = rem - yy * FM;
        const int q   = rem >> 1;

        const float2* pb = (const float2*)(preds + (size_t)(n * NA + a) * 25 * FMFM) + q;
        const float2* cb = (const float2*)(cls_t + (size_t)(n * NA + a) * NC * FMFM) + q;
        const float2* lb = (const float2*)(loc_t + (size_t)(n * NA + a) * 4  * FMFM) + q;

        float2 lacc = make_float2(0.f, 0.f);

        float2 s = make_float2(0.f, 0.f);
        #pragma unroll 5
        for (int c = 0; c < NC; ++c) {
            float2 v = pb[(5 + c) * Q2];
            s.x += __expf(v.x);
            s.y += __expf(v.y);
        }
        float2 inv = make_float2(frcp(s.x), frcp(s.y));

        const float2* pbo = pb;
        asm volatile("" : "+v"(pbo));

        float2 cmax = make_float2(0.f, 0.f);
        #pragma unroll 4
        for (int c = 0; c < NC; ++c) {
            float2 lv = pbo[(5 + c) * Q2];
            float2 tv = cb[c * Q2];
            CLSJ(x) CLSJ(y)
        }

        float2 pos, wgt;
        pos.x = cmax.x > 0.f ? 1.f : 0.f;  wgt.x = cmax.x > 0.f ? 1.f : 0.1f;
        pos.y = cmax.y > 0.f ? 1.f : 0.f;  wgt.y = cmax.y > 0.f ? 1.f : 0.1f;
        posn = pos.x + pos.y;

        float2 P0 = pb[0 * Q2], P1 = pb[1 * Q2], P2 = pb[2 * Q2];
        float2 P3 = pb[3 * Q2], P4 = pb[4 * Q2];
        float2 T0 = lb[0 * Q2], T1 = lb[1 * Q2], T2 = lb[2 * Q2], T3 = lb[3 * Q2];

        const float aw = anchors[a * 2 + 0];
        const float ah = anchors[a * 2 + 1];

        float2 px1, py1, px2, py2, ap, ib, db;
        HEADJ(x, 0) HEADJ(y, 1)
        ib = make_float2(0.f, 0.f);
        db = make_float2(1.f, 1.f);

        #pragma unroll 4
        for (int tb = 0; tb < NM; ++tb) {
            float4 B = sbox[tb];
            float sa = sarea[tb];
            IOUJ(x) IOUJ(y)
        }
        IOULOSSJ(x) IOULOSSJ(y)

        loss = lacc.x + lacc.y;
    }

    double dl = (double)loss;
    double dp = (double)posn;
    #pragma unroll
    for (int off = 32; off > 0; off >>= 1) {
        dl += __shfl_down(dl, off);
        dp += __shfl_down(dp, off);
    }
    const int wave = tid >> 6, lane = tid & 63;
    if (lane == 0) { wsum[wave] = dl; wpos[wave] = dp; }
    __syncthreads();
    if (tid == 0) {
        double tl = 0.0, tp = 0.0;
        #pragma unroll
        for (int w = 0; w < BLOCK / 64; ++w) { tl += wsum[w]; tp += wpos[w]; }
        atomicAdd(&acc[0], tl);
        atomicAdd(&acc[1], tp);
    }
}

// ============ PROBE A: r7 load pattern, ALL math sunk (no DCE) =============
__global__ __launch_bounds__(BLOCK) void yolo_loads(
    const float* __restrict__ preds,
    const float* __restrict__ loc_t,
    const float* __restrict__ cls_t,
    const float4* __restrict__ box_t,
    const float* __restrict__ anchors)
{
    __shared__ float4 sbox[NM];
    __shared__ float  sarea[NM];

    const int n = blockIdx.y;
    const int tid = threadIdx.x;

    if (tid < NM) {
        float4 b = box_t[n * NM + tid];
        sbox[tid] = b;
        sarea[tid] = (b.z - b.x) * (b.w - b.y);
    }
    __syncthreads();

    const int t = blockIdx.x * BLOCK + tid;
    if (t < TPI2) {
        const int g   = t * 2;
        const int a   = g / FMFM;
        const int rem = g - a * FMFM;
        const int q   = rem >> 1;

        const float2* pb = (const float2*)(preds + (size_t)(n * NA + a) * 25 * FMFM) + q;
        const float2* cb = (const float2*)(cls_t + (size_t)(n * NA + a) * NC * FMFM) + q;
        const float2* lb = (const float2*)(loc_t + (size_t)(n * NA + a) * 4  * FMFM) + q;

        #pragma unroll 5
        for (int c = 0; c < NC; ++c) sink2(pb[(5 + c) * Q2]);

        const float2* pbo = pb;
        asm volatile("" : "+v"(pbo));

        #pragma unroll 4
        for (int c = 0; c < NC; ++c) { sink2(pbo[(5 + c) * Q2]); sink2(cb[c * Q2]); }

        sink2(pb[0 * Q2]); sink2(pb[1 * Q2]); sink2(pb[2 * Q2]);
        sink2(pb[3 * Q2]); sink2(pb[4 * Q2]);
        sink2(lb[0 * Q2]); sink2(lb[1 * Q2]); sink2(lb[2 * Q2]); sink2(lb[3 * Q2]);
        asm volatile("" :: "v"(sarea[tid & (NM - 1)]));
    }
}

// ====== PROBE B: contiguous float4 grid-stride streaming calibration ======
// Reads the same 169 MB as the real kernel, textbook-coalesced.
__global__ __launch_bounds__(BLOCK) void yolo_stream(
    const float4* __restrict__ preds,   // 64*125*2704/4  = 5,408,000 float4
    const float4* __restrict__ loc_t,   // 64*20*2704/4   =   865,280 float4
    const float4* __restrict__ cls_t)   // 64*100*2704/4  = 4,326,400 float4
{
    const size_t np = (size_t)N_IMG * NA * 25 * FMFM / 4;
    const size_t nl = (size_t)N_IMG * NA * 4  * FMFM / 4;
    const size_t nc = (size_t)N_IMG * NA * NC * FMFM / 4;
    const size_t stride = (size_t)gridDim.x * BLOCK;
    const size_t t0 = (size_t)blockIdx.x * BLOCK + threadIdx.x;

    for (size_t i = t0; i < np; i += stride) sink4(preds[i]);
    for (size_t i = t0; i < nl; i += stride) sink4(loc_t[i]);
    for (size_t i = t0; i < nc; i += stride) sink4(cls_t[i]);
}

__global__ void yolo_loss_finalize(const double* __restrict__ acc,
                                   float* __restrict__ out) {
    out[0] = (float)(acc[0] / acc[1]);
}

extern "C" void kernel_launch(void* const* d_in, const int* in_sizes, int n_in,
                              void* d_out, int out_size, void* d_ws, size_t ws_size,
                              hipStream_t stream) {
    const float*  preds   = (const float*)d_in[0];
    const float*  loc_t   = (const float*)d_in[1];
    const float*  cls_t   = (const float*)d_in[2];
    const float4* box_t   = (const float4*)d_in[3];
    const float*  anchors = (const float*)d_in[4];
    double* acc = (double*)d_ws;

    hipMemsetAsync(d_ws, 0, 2 * sizeof(double), stream);

    dim3 grid(BX2, N_IMG);
    // Real kernel first (same cache conditions as rounds 6-8 for continuity).
    yolo_full<<<grid, BLOCK, 0, stream>>>(preds, loc_t, cls_t, box_t, anchors, acc);
    yolo_loss_finalize<<<1, 1, 0, stream>>>(acc, (float*)d_out);
    // Probe A: identical gather structure, math removed (values asm-sunk).
    yolo_loads<<<grid, BLOCK, 0, stream>>>(preds, loc_t, cls_t, box_t, anchors);
    // Probe B: textbook streaming read of the same bytes.
    yolo_stream<<<2048, BLOCK, 0, stream>>>((const float4*)preds,
                                            (const float4*)loc_t,
                                            (const float4*)cls_t);
}

// Round 11
// 198.337 us; speedup vs baseline: 1.7403x; 1.3757x over previous
//
#include <hip/hip_runtime.h>

// Problem constants: N=64, A=5, C=20, FM=52, M=32
#define N_IMG 64
#define NA 5
#define NC 20
#define FM 52
#define NM 32
#define FMFM (FM * FM)                  // 2704 (even)
#define Q2 (FMFM / 2)                   // 1352 float2 per channel plane
#define CELLS (NA * FMFM)               // 13520
#define TPI2 (CELLS / 2)                // 6760 threads/image, 2 cells each
#define BLOCK 256
#define BX2 ((TPI2 + BLOCK - 1) / BLOCK) // 27

__device__ __forceinline__ float frcp(float x) { return __builtin_amdgcn_rcpf(x); }
__device__ __forceinline__ float sl1(float a, float b) {
    float d = a - b;
    float ad = fabsf(d);
    return ad < 1.0f ? 0.5f * d * d : ad - 0.5f;
}

// exp-in-place pass 2: probability from the already-exponentiated logit.
#define CLSJ(C) {                                                             \
    cmax.C = fmaxf(cmax.C, tv.C);                                             \
    float pr = lv.C * inv.C;                                                  \
    lacc.C += tv.C > 0.0f ? sl1(pr, tv.C) : 0.0f; }

#define HEADJ(C, JX) {                                                        \
    float sx = frcp(1.0f + __expf(-P0.C));                                    \
    float sy = frcp(1.0f + __expf(-P1.C));                                    \
    float ew = __expf(P2.C);                                                  \
    float eh = __expf(P3.C);                                                  \
    lacc.C += pos.C * (sl1(sx, T0.C) + sl1(sy, T1.C) +                        \
                       sl1(ew, T2.C) + sl1(eh, T3.C));                        \
    float bx = sx + (float)(xx + JX);                                         \
    float by = sy + (float)yy;                                                \
    float bw = aw * ew, bh = ah * eh;                                         \
    px1.C = bx - 0.5f * bw; py1.C = by - 0.5f * bh;                           \
    px2.C = bx + 0.5f * bw; py2.C = by + 0.5f * bh;                           \
    ap.C  = (px2.C - px1.C) * (py2.C - py1.C); }

#define IOUJ(C) {                                                             \
    float lx = fmaxf(px1.C, B.x), ly = fmaxf(py1.C, B.y);                     \
    float rx = fminf(px2.C, B.z), ry = fminf(py2.C, B.w);                     \
    float w_ = fmaxf(rx - lx, 0.0f), h_ = fmaxf(ry - ly, 0.0f);               \
    float it = w_ * h_;                                                       \
    float dn = ap.C + sa - it;                                                \
    bool gt = it * db.C > ib.C * dn;                                          \
    ib.C = gt ? it : ib.C;                                                    \
    db.C = gt ? dn : db.C; }

#define IOULOSSJ(C) {                                                         \
    float best  = ib.C * frcp(db.C);                                          \
    float ipred = frcp(1.0f + __expf(-P4.C));                                 \
    lacc.C += sl1(ipred * wgt.C, best * wgt.C); }

// Mega-batch structure (r10 discriminator: identical loads with no dependent
// math ran ~3x faster than the interleaved kernel -> serialization of
// load-batches with math was the cost). ALL 49 float2 loads are issued
// before any consuming math; sched_barrier(0) forbids interleaving.
// launch_bounds(256,2): 256-VGPR budget -> the 98 in-flight results CANNOT
// spill (the r3/r5 trap was a tight occupancy cap forcing scratch).
__global__ __launch_bounds__(BLOCK, 2) void yolo_loss_main(
    const float* __restrict__ preds,     // [N, A*25, FM, FM]
    const float* __restrict__ loc_t,     // [N, A, 4, FM, FM]
    const float* __restrict__ cls_t,     // [N, A, C, FM, FM]
    const float4* __restrict__ box_t,    // [N, M] xyxy
    const float* __restrict__ anchors,   // [A, 2]
    double* __restrict__ acc)            // acc[0]=loss sum, acc[1]=num_pos
{
    __shared__ float4 sbox[NM];
    __shared__ float  sarea[NM];
    __shared__ double wsum[BLOCK / 64];
    __shared__ double wpos[BLOCK / 64];

    const int n = blockIdx.y;
    const int tid = threadIdx.x;

    if (tid < NM) {
        float4 b = box_t[n * NM + tid];
        sbox[tid] = b;
        sarea[tid] = (b.z - b.x) * (b.w - b.y);
    }
    __syncthreads();

    const int t = blockIdx.x * BLOCK + tid;
    float loss = 0.0f, posn = 0.0f;

    if (t < TPI2) {
        const int g   = t * 2;
        const int a   = g / FMFM;
        const int rem = g - a * FMFM;     // y*FM + x, x even
        const int yy  = rem / FM;
        const int xx  = rem - yy * FM;
        const int q   = rem >> 1;         // float2 index in plane

        const float2* pb = (const float2*)(preds + (size_t)(n * NA + a) * 25 * FMFM) + q;
        const float2* cb = (const float2*)(cls_t + (size_t)(n * NA + a) * NC * FMFM) + q;
        const float2* lb = (const float2*)(loc_t + (size_t)(n * NA + a) * 4  * FMFM) + q;

        // ================= PREFETCH: all 49 loads, zero math =================
        // Constant-index unrolled arrays stay in registers (rule #20).
        float2 l[NC], ct[NC];
        #pragma unroll
        for (int c = 0; c < NC; ++c) l[c]  = pb[(5 + c) * Q2];
        #pragma unroll
        for (int c = 0; c < NC; ++c) ct[c] = cb[c * Q2];
        float2 P0 = pb[0 * Q2], P1 = pb[1 * Q2], P2 = pb[2 * Q2];
        float2 P3 = pb[3 * Q2], P4 = pb[4 * Q2];
        float2 T0 = lb[0 * Q2], T1 = lb[1 * Q2], T2 = lb[2 * Q2], T3 = lb[3 * Q2];

        // Fence: no math hoists above, no load sinks below. One round-trip.
        __builtin_amdgcn_sched_barrier(0);

        // ========================= MATH (reg-resident) =======================
        float2 lacc = make_float2(0.f, 0.f);

        // Softmax denominator, no max-subtraction (validated r7: absmax 0.0).
        // exp in place: l[c] <- exp(l[c]); reused for probabilities below.
        float2 s = make_float2(0.f, 0.f);
        #pragma unroll
        for (int c = 0; c < NC; ++c) {
            l[c].x = __expf(l[c].x);  s.x += l[c].x;
            l[c].y = __expf(l[c].y);  s.y += l[c].y;
        }
        float2 inv = make_float2(frcp(s.x), frcp(s.y));

        // Positivity + cls loss.
        float2 cmax = make_float2(0.f, 0.f);
        #pragma unroll
        for (int c = 0; c < NC; ++c) {
            float2 lv = l[c];
            float2 tv = ct[c];
            CLSJ(x) CLSJ(y)
        }

        float2 pos, wgt;
        pos.x = cmax.x > 0.f ? 1.f : 0.f;  wgt.x = cmax.x > 0.f ? 1.f : 0.1f;
        pos.y = cmax.y > 0.f ? 1.f : 0.f;  wgt.y = cmax.y > 0.f ? 1.f : 0.1f;
        posn = pos.x + pos.y;

        // Head: loc loss + box decode.
        const float aw = anchors[a * 2 + 0];
        const float ah = anchors[a * 2 + 1];

        float2 px1, py1, px2, py2, ap, ib, db;
        HEADJ(x, 0) HEADJ(y, 1)
        ib = make_float2(0.f, 0.f);
        db = make_float2(1.f, 1.f);

        // IoU argmax over 32 boxes, division-free compare.
        #pragma unroll 4
        for (int tb = 0; tb < NM; ++tb) {
            float4 B = sbox[tb];
            float sa = sarea[tb];
            IOUJ(x) IOUJ(y)
        }
        IOULOSSJ(x) IOULOSSJ(y)

        loss = lacc.x + lacc.y;
    }

    // ---- Reduction: wave shfl (double) -> LDS -> one atomic per block ----
    double dl = (double)loss;
    double dp = (double)posn;
    #pragma unroll
    for (int off = 32; off > 0; off >>= 1) {
        dl += __shfl_down(dl, off);
        dp += __shfl_down(dp, off);
    }
    const int wave = tid >> 6, lane = tid & 63;
    if (lane == 0) { wsum[wave] = dl; wpos[wave] = dp; }
    __syncthreads();
    if (tid == 0) {
        double tl = 0.0, tp = 0.0;
        #pragma unroll
        for (int w = 0; w < BLOCK / 64; ++w) { tl += wsum[w]; tp += wpos[w]; }
        atomicAdd(&acc[0], tl);
        atomicAdd(&acc[1], tp);
    }
}

__global__ void yolo_loss_finalize(const double* __restrict__ acc,
                                   float* __restrict__ out) {
    out[0] = (float)(acc[0] / acc[1]);
}

extern "C" void kernel_launch(void* const* d_in, const int* in_sizes, int n_in,
                              void* d_out, int out_size, void* d_ws, size_t ws_size,
                              hipStream_t stream) {
    const float*  preds   = (const float*)d_in[0];
    const float*  loc_t   = (const float*)d_in[1];
    const float*  cls_t   = (const float*)d_in[2];
    const float4* box_t   = (const float4*)d_in[3];
    const float*  anchors = (const float*)d_in[4];
    double* acc = (double*)d_ws;

    hipMemsetAsync(d_ws, 0, 2 * sizeof(double), stream);

    dim3 grid(BX2, N_IMG);
    yolo_loss_main<<<grid, BLOCK, 0, stream>>>(preds, loc_t, cls_t, box_t,
                                               anchors, acc);
    yolo_loss_finalize<<<1, 1, 0, stream>>>(acc, (float*)d_out);
}